// Round 1
// baseline (291.443 us; speedup 1.0000x reference)
//
#include <hip/hip_runtime.h>
#include <math.h>

// Problem constants (fixed by reference setup_inputs)
#define Bb   2
#define Cc   19
#define Hh   128
#define Ww   128
#define CHc  64
#define HWs  (Hh*Ww)          // 16384
#define NPIX (Bb*HWs)         // 32768
#define Kk   7
#define K2   49
#define PADk 3
#define TOPKk 8
#define EPSf 1e-8f

// ---------------- Kernel P: softmax(p) + feature norms ----------------
__global__ __launch_bounds__(256) void precompute_kernel(
    const float* __restrict__ logits,
    const float* __restrict__ xsrc,
    const float* __restrict__ xema,
    float* __restrict__ p,
    float* __restrict__ nsrc,
    float* __restrict__ nema) {
  int idx = blockIdx.x * blockDim.x + threadIdx.x;
  if (idx >= NPIX) return;
  int b = idx / HWs, hw = idx - b * HWs;

  // softmax over 19 classes
  const float* lg = logits + (size_t)b * Cc * HWs + hw;
  float v[Cc];
  float m = -INFINITY;
#pragma unroll
  for (int c = 0; c < Cc; c++) { v[c] = lg[c * HWs]; m = fmaxf(m, v[c]); }
  float s = 0.f;
#pragma unroll
  for (int c = 0; c < Cc; c++) { v[c] = expf(v[c] - m); s += v[c]; }
  float inv = 1.0f / s;
  float* pp = p + (size_t)b * Cc * HWs + hw;
#pragma unroll
  for (int c = 0; c < Cc; c++) pp[c * HWs] = v[c] * inv;

  // L2 norms of the 64-ch feature vectors
  const float* xs = xsrc + (size_t)b * CHc * HWs + hw;
  const float* xe = xema + (size_t)b * CHc * HWs + hw;
  float ss = 0.f, se = 0.f;
#pragma unroll 8
  for (int c = 0; c < CHc; c++) {
    float a = xs[c * HWs]; ss += a * a;
    float e = xe[c * HWs]; se += e * e;
  }
  nsrc[idx] = sqrtf(ss);
  nema[idx] = sqrtf(se);
}

// ---------------- Kernel S: source pos/neg similarity means ----------------
// wave per pixel (grid-stride); lane = neighbor index (49 of 64 lanes active)
__global__ __launch_bounds__(256) void src_kernel(
    const float* __restrict__ x,    // x_src
    const int*   __restrict__ gt,
    const float* __restrict__ nrm,  // norm of x_src
    float* __restrict__ acc) {
  int tid   = blockIdx.x * blockDim.x + threadIdx.x;
  int lane  = threadIdx.x & 63;
  int wave  = tid >> 6;
  int nwaves = (gridDim.x * blockDim.x) >> 6;
  int dh = lane / Kk - PADk;
  int dw = lane % Kk - PADk;

  float psum = 0.f, pcnt = 0.f, nsum = 0.f, ncnt = 0.f;

  for (int pix = wave; pix < NPIX; pix += nwaves) {
    int b = pix / HWs, hw = pix - b * HWs;
    int h = hw / Ww,  w = hw - h * Ww;
    int hn = h + dh, wn = w + dw;
    bool inb = (lane < K2) && ((unsigned)hn < (unsigned)Hh) && ((unsigned)wn < (unsigned)Ww);
    int hnw = hn * Ww + wn;

    float dot = 0.f;
    if (inb) {
      const float* xc = x + (size_t)b * CHc * HWs + hw;
      const float* xn = x + (size_t)b * CHc * HWs + hnw;
#pragma unroll 8
      for (int c = 0; c < CHc; c++) dot += xc[c * HWs] * xn[c * HWs];
    }

    if (lane < K2) {
      int gtc = gt[b * HWs + hw];
      if (gtc != 255) {
        float sim = 0.f;
        int gtn = 0;  // zero-padded gt for OOB
        if (inb) {
          sim = dot / (fmaxf(nrm[b * HWs + hnw], EPSf) * fmaxf(nrm[pix], EPSf));
          gtn = gt[b * HWs + hnw];
        }
        if (gtn == gtc) { psum += sim; pcnt += 1.f; }
        else            { nsum += sim; ncnt += 1.f; }
      }
    }
  }

  // 64-lane butterfly reduce
#pragma unroll
  for (int off = 32; off; off >>= 1) {
    psum += __shfl_xor(psum, off);
    pcnt += __shfl_xor(pcnt, off);
    nsum += __shfl_xor(nsum, off);
    ncnt += __shfl_xor(ncnt, off);
  }
  __shared__ float sacc[4][4];
  int wib = threadIdx.x >> 6;
  if (lane == 0) { sacc[wib][0] = psum; sacc[wib][1] = pcnt; sacc[wib][2] = nsum; sacc[wib][3] = ncnt; }
  __syncthreads();
  if (threadIdx.x < 4) {
    float s = sacc[0][threadIdx.x] + sacc[1][threadIdx.x] + sacc[2][threadIdx.x] + sacc[3][threadIdx.x];
    atomicAdd(&acc[threadIdx.x], s);
  }
}

// ---------------- Kernel T: target top-k selected losses ----------------
__global__ __launch_bounds__(256) void trg_kernel(
    const float* __restrict__ x,    // x_ema
    const float* __restrict__ p,    // softmax probs [B,19,H,W]
    const float* __restrict__ mix,  // mix_masks [B,1,H,W]
    const float* __restrict__ nrm,  // norm of x_ema
    float* __restrict__ acc) {
  int tid   = blockIdx.x * blockDim.x + threadIdx.x;
  int lane  = threadIdx.x & 63;
  int wave  = tid >> 6;
  int nwaves = (gridDim.x * blockDim.x) >> 6;
  int dh = lane / Kk - PADk;
  int dw = lane % Kk - PADk;

  float lpsum = 0.f, lnsum = 0.f, cnt = 0.f;

  for (int pix = wave; pix < NPIX; pix += nwaves) {
    // ign_trg = (1 - mix) > 0.5  <=>  mix < 0.5 ; wave-uniform
    if (!(mix[pix] < 0.5f)) continue;

    int b = pix / HWs, hw = pix - b * HWs;
    int h = hw / Ww,  w = hw - h * Ww;
    int hn = h + dh, wn = w + dw;
    bool inb = (lane < K2) && ((unsigned)hn < (unsigned)Hh) && ((unsigned)wn < (unsigned)Ww);
    int hnw = hn * Ww + wn;

    float sim = 0.f;
    float cp  = 1.0f / (float)Cc;  // OOB: softmax(0-logits) uniform -> <p, 1/C> = 1/C
    if (inb) {
      const float* xc = x + (size_t)b * CHc * HWs + hw;
      const float* xn = x + (size_t)b * CHc * HWs + hnw;
      float dot = 0.f;
#pragma unroll 8
      for (int c = 0; c < CHc; c++) dot += xc[c * HWs] * xn[c * HWs];
      sim = dot / (fmaxf(nrm[b * HWs + hnw], EPSf) * fmaxf(nrm[pix], EPSf));

      const float* pc = p + (size_t)b * Cc * HWs + hw;
      const float* pn = p + (size_t)b * Cc * HWs + hnw;
      float c2 = 0.f;
#pragma unroll
      for (int c = 0; c < Cc; c++) c2 += pc[c * HWs] * pn[c * HWs];
      cp = c2;
    }

    float vmax = (lane < K2) ? sim : -INFINITY;
    float vmin = (lane < K2) ? sim :  INFINITY;
    float spos = 0.f, sneg = 0.f;

    // top-(TOPK+1) most similar: sum v * cp
#pragma unroll
    for (int t = 0; t < TOPKk + 1; t++) {
      float v = vmax; int i = lane;
#pragma unroll
      for (int off = 32; off; off >>= 1) {
        float ov = __shfl_xor(v, off);
        int   oi = __shfl_xor(i, off);
        if (ov > v || (ov == v && oi < i)) { v = ov; i = oi; }
      }
      float cps = __shfl(cp, i);
      spos += v * cps;
      if (lane == i) vmax = -INFINITY;
    }
    // bottom-TOPK least similar: sum (1-v)*(1-cp)
#pragma unroll
    for (int t = 0; t < TOPKk; t++) {
      float v = vmin; int i = lane;
#pragma unroll
      for (int off = 32; off; off >>= 1) {
        float ov = __shfl_xor(v, off);
        int   oi = __shfl_xor(i, off);
        if (ov < v || (ov == v && oi < i)) { v = ov; i = oi; }
      }
      float cps = __shfl(cp, i);
      sneg += (1.0f - v) * (1.0f - cps);
      if (lane == i) vmin = INFINITY;
    }

    if (lane == 0) { lpsum -= spos; lnsum -= sneg; cnt += 1.f; }
  }

  // only lane 0 of each wave holds nonzero partials
  __shared__ float sacc[4][4];
  int wib = threadIdx.x >> 6;
  if (lane == 0) { sacc[wib][0] = lpsum; sacc[wib][1] = lnsum; sacc[wib][2] = cnt; sacc[wib][3] = 0.f; }
  __syncthreads();
  if (threadIdx.x < 3) {
    float s = sacc[0][threadIdx.x] + sacc[1][threadIdx.x] + sacc[2][threadIdx.x] + sacc[3][threadIdx.x];
    atomicAdd(&acc[4 + threadIdx.x], s);
  }
}

// ---------------- Kernel F: combine to 4 outputs ----------------
__global__ void finish_kernel(const float* __restrict__ acc, float* __restrict__ out) {
  if (threadIdx.x == 0 && blockIdx.x == 0) {
    float src_pos = acc[0] / fmaxf(acc[1], 1.0f);
    float src_neg = acc[2] / fmaxf(acc[3], 1.0f);
    float cntpix  = acc[6];
    float lp = acc[4] / fmaxf(9.0f * cntpix, 1.0f);
    float ln = acc[5] / fmaxf(8.0f * cntpix, 1.0f);
    out[0] = -src_pos;
    out[1] =  src_neg;
    out[2] =  lp;
    out[3] =  ln;
  }
}

extern "C" void kernel_launch(void* const* d_in, const int* in_sizes, int n_in,
                              void* d_out, int out_size, void* d_ws, size_t ws_size,
                              hipStream_t stream) {
  const float* logits = (const float*)d_in[0];  // [2,19,128,128]
  const int*   gt     = (const int*)  d_in[1];  // [2,1,128,128]
  const float* xema   = (const float*)d_in[2];  // [2,64,128,128]
  const float* xsrc   = (const float*)d_in[3];  // [2,64,128,128]
  const float* mix    = (const float*)d_in[4];  // [2,1,128,128]
  // d_in[5] img_trg unused
  float* out = (float*)d_out;

  float* ws   = (float*)d_ws;
  float* acc  = ws;                 // 8 floats: psum,pcnt,nsum,ncnt,lpsum,lnsum,cnt,pad
  float* nsrc = ws + 8;             // NPIX
  float* nema = nsrc + NPIX;        // NPIX
  float* p    = nema + NPIX;        // Bb*Cc*HWs = 622592 floats
  // total ws use: (8 + 2*32768 + 622592)*4 B ~= 2.75 MB

  hipMemsetAsync(acc, 0, 8 * sizeof(float), stream);

  precompute_kernel<<<(NPIX + 255) / 256, 256, 0, stream>>>(logits, xsrc, xema, p, nsrc, nema);
  src_kernel<<<1024, 256, 0, stream>>>(xsrc, gt, nsrc, acc);
  trg_kernel<<<1024, 256, 0, stream>>>(xema, p, mix, nema, acc);
  finish_kernel<<<1, 64, 0, stream>>>(acc, out);
}

// Round 2
// 135.521 us; speedup vs baseline: 2.1505x; 2.1505x over previous
//
#include <hip/hip_runtime.h>
#include <math.h>

// Problem constants (fixed by reference setup_inputs)
#define Bb   2
#define Cc   19
#define Hh   128
#define Ww   128
#define CHc  64
#define HWs  (Hh*Ww)          // 16384
#define NPIX (Bb*HWs)         // 32768
#define Kk   7
#define K2   49
#define PADk 3
#define EPSf 1e-8f
#define FPAD 68               // padded feature stride (floats), zero-padded 64..67
#define PPAD 20               // padded prob stride (floats), p[19]=0

// ---------- Kernel P1: normalize + transpose features to [pix][FPAD] ----------
// grid (256, 2, 2): x = 64-pixel block, y = batch, z = {0: x_src, 1: x_ema}
__global__ __launch_bounds__(256) void feat_kernel(
    const float* __restrict__ xsrc, const float* __restrict__ xema,
    float* __restrict__ osrc, float* __restrict__ oema) {
  __shared__ float tile[64 * 65];
  __shared__ float part[256];
  __shared__ float invn[64];
  const float* in = blockIdx.z ? xema : xsrc;
  float* out = blockIdx.z ? oema : osrc;
  int b = blockIdx.y;
  int pix0 = blockIdx.x * 64;
  int t = threadIdx.x, w = t >> 6, l = t & 63;

  const float* src = in + (size_t)b * CHc * HWs + pix0;
#pragma unroll
  for (int cc = 0; cc < 16; cc++) {
    int c = cc * 4 + w;
    tile[c * 65 + l] = src[(size_t)c * HWs + l];   // coalesced per wave
  }
  __syncthreads();
  // partial norms: wave w sums channels [w*16, w*16+16) for pixel l
  float s = 0.f;
#pragma unroll
  for (int c = w * 16; c < w * 16 + 16; c++) { float a = tile[c * 65 + l]; s += a * a; }
  part[w * 64 + l] = s;
  __syncthreads();
  if (t < 64) {
    float n = part[t] + part[64 + t] + part[128 + t] + part[192 + t];
    invn[t] = 1.0f / fmaxf(sqrtf(n), EPSf);
  }
  __syncthreads();
  float* ob = out + (size_t)(b * HWs + pix0) * FPAD;
#pragma unroll
  for (int j = 0; j < 16; j++) {
    int px = j * 4 + w;                       // pixel within block
    ob[(size_t)px * FPAD + l] = tile[l * 65 + px] * invn[px];  // lane = channel, coalesced
  }
  { // zero the pad channels 64..67
    int px = t >> 2, z = t & 3;
    ob[(size_t)px * FPAD + 64 + z] = 0.f;
  }
}

// ---------- Kernel P2: softmax + transpose to [pix][PPAD] ----------
// thread per pixel; 256 px per block
__global__ __launch_bounds__(256) void prob_kernel(
    const float* __restrict__ logits, float* __restrict__ pt) {
  __shared__ float lp[256 * 21];
  int t = threadIdx.x;
  int gpix = blockIdx.x * 256 + t;
  int b = gpix >> 14, hw = gpix & (HWs - 1);
  const float* lg = logits + (size_t)b * Cc * HWs + hw;
  float v[Cc]; float m = -INFINITY;
#pragma unroll
  for (int c = 0; c < Cc; c++) { v[c] = lg[(size_t)c * HWs]; m = fmaxf(m, v[c]); }
  float s = 0.f;
#pragma unroll
  for (int c = 0; c < Cc; c++) { v[c] = expf(v[c] - m); s += v[c]; }
  float inv = 1.0f / s;
#pragma unroll
  for (int c = 0; c < Cc; c++) lp[t * 21 + c] = v[c] * inv;
  __syncthreads();
  float* ob = pt + (size_t)blockIdx.x * 256 * PPAD;
  for (int idx = t; idx < 256 * PPAD; idx += 256) {
    int px = idx / PPAD, c = idx - px * PPAD;
    ob[idx] = (c < Cc) ? lp[px * 21 + c] : 0.f;   // coalesced, pad = 0
  }
}

// ---------- Kernel ST: fused source-sim + target-topk, wave per pixel ----------
__global__ __launch_bounds__(256) void st_kernel(
    const float* __restrict__ fsrc, const float* __restrict__ fema,
    const float* __restrict__ pt,
    const int* __restrict__ gt, const float* __restrict__ mix,
    float* __restrict__ acc) {
  int bid = blockIdx.x;
  int swz = (bid & 7) * 128 + (bid >> 3);         // XCD-contiguous (1024 % 8 == 0)
  int b = swz >> 9, tl = swz & 511;
  int h0 = (tl >> 4) * 4, w0 = (tl & 15) * 8;     // 4x8 pixel tile
  int t = threadIdx.x, wv = t >> 6, lane = t & 63;
  int dh = lane / Kk - PADk, dw = lane % Kk - PADk;
  bool lactive = lane < K2;
  float psum = 0, pcnt = 0, nsum = 0, ncnt = 0, posa = 0, nega = 0, cnt = 0;
  const size_t bbase = (size_t)b * HWs;

#pragma unroll 1
  for (int j = 0; j < 8; j++) {
    int li = (j << 2) | wv;
    int h = h0 + (li >> 3), w = w0 + (li & 7);
    int hw = h * Ww + w;
    int hn = h + dh, wn = w + dw;
    bool inb = lactive & ((unsigned)hn < (unsigned)Hh) & ((unsigned)wn < (unsigned)Ww);
    int hnc = min(max(hn, 0), Hh - 1), wnc = min(max(wn, 0), Ww - 1);
    int hwn = hnc * Ww + wnc;                     // clamped: loads always valid

    // --- source cosine sim (pre-normalized dot) ---
    const float4* sc = (const float4*)(fsrc + (bbase + hw) * FPAD);
    const float4* sn = (const float4*)(fsrc + (bbase + hwn) * FPAD);
    float dots = 0.f;
#pragma unroll
    for (int k2 = 0; k2 < 17; k2++) {
      float4 a = sc[k2], bb = sn[k2];
      dots += a.x * bb.x + a.y * bb.y + a.z * bb.z + a.w * bb.w;
    }
    float sims = inb ? dots : 0.f;                // zero-pad unfold -> sim 0
    int gtc = gt[bbase + hw];
    int gtn = inb ? gt[bbase + hwn] : 0;          // zero-pad unfold -> gt 0
    if (lactive && gtc != 255) {
      if (gtn == gtc) { psum += sims; pcnt += 1.f; }
      else            { nsum += sims; ncnt += 1.f; }
    }

    // --- target branch (wave-uniform mask) ---
    if (mix[bbase + hw] < 0.5f) {
      const float4* ec = (const float4*)(fema + (bbase + hw) * FPAD);
      const float4* en = (const float4*)(fema + (bbase + hwn) * FPAD);
      float dote = 0.f;
#pragma unroll
      for (int k2 = 0; k2 < 17; k2++) {
        float4 a = ec[k2], bb = en[k2];
        dote += a.x * bb.x + a.y * bb.y + a.z * bb.z + a.w * bb.w;
      }
      const float4* pc = (const float4*)(pt + (bbase + hw) * PPAD);
      const float4* pn = (const float4*)(pt + (bbase + hwn) * PPAD);
      float dotp = 0.f;
#pragma unroll
      for (int k2 = 0; k2 < 5; k2++) {
        float4 a = pc[k2], bb = pn[k2];
        dotp += a.x * bb.x + a.y * bb.y + a.z * bb.z + a.w * bb.w;
      }
      float v   = lactive ? (inb ? dote : 0.f)          : -INFINITY;
      float cpv = lactive ? (inb ? dotp : (1.0f / Cc))  : 0.f;

      // bitonic sort descending by v, carrying cpv (ties only among identical OOB pairs)
#pragma unroll
      for (int k = 2; k <= 64; k <<= 1) {
#pragma unroll
        for (int jj = k >> 1; jj > 0; jj >>= 1) {
          float ov  = __shfl_xor(v, jj);
          float ocp = __shfl_xor(cpv, jj);
          bool takeMax = ((lane & k) == 0) == ((lane & jj) == 0);
          bool sw = takeMax ? (ov > v) : (ov < v);
          if (sw) { v = ov; cpv = ocp; }
        }
      }
      if (lane < 9)                 posa += v * cpv;                   // top-9 most similar
      if (lane >= 41 && lane < 49)  nega += (1.f - v) * (1.f - cpv);   // bottom-8 of 49 reals
      if (lane == 0)                cnt += 1.f;
    }
  }

  // wave butterfly reduce of 7 accumulators
#pragma unroll
  for (int off = 32; off; off >>= 1) {
    psum += __shfl_xor(psum, off); pcnt += __shfl_xor(pcnt, off);
    nsum += __shfl_xor(nsum, off); ncnt += __shfl_xor(ncnt, off);
    posa += __shfl_xor(posa, off); nega += __shfl_xor(nega, off);
    cnt  += __shfl_xor(cnt,  off);
  }
  __shared__ float sacc[4][8];
  if (lane == 0) {
    sacc[wv][0] = psum; sacc[wv][1] = pcnt; sacc[wv][2] = nsum; sacc[wv][3] = ncnt;
    sacc[wv][4] = posa; sacc[wv][5] = nega; sacc[wv][6] = cnt;
  }
  __syncthreads();
  if (t < 7) {
    float s = sacc[0][t] + sacc[1][t] + sacc[2][t] + sacc[3][t];
    atomicAdd(&acc[t], s);
  }
}

// ---------- Kernel F: combine ----------
__global__ void finish_kernel(const float* __restrict__ acc, float* __restrict__ out) {
  if (threadIdx.x == 0 && blockIdx.x == 0) {
    float src_pos = acc[0] / fmaxf(acc[1], 1.0f);
    float src_neg = acc[2] / fmaxf(acc[3], 1.0f);
    float cntpix  = acc[6];
    out[0] = -src_pos;
    out[1] =  src_neg;
    out[2] = -(acc[4] / fmaxf(9.0f * cntpix, 1.0f));
    out[3] = -(acc[5] / fmaxf(8.0f * cntpix, 1.0f));
  }
}

extern "C" void kernel_launch(void* const* d_in, const int* in_sizes, int n_in,
                              void* d_out, int out_size, void* d_ws, size_t ws_size,
                              hipStream_t stream) {
  const float* logits = (const float*)d_in[0];  // [2,19,128,128]
  const int*   gt     = (const int*)  d_in[1];  // [2,1,128,128]
  const float* xema   = (const float*)d_in[2];  // [2,64,128,128]
  const float* xsrc   = (const float*)d_in[3];  // [2,64,128,128]
  const float* mix    = (const float*)d_in[4];  // [2,1,128,128]
  float* out = (float*)d_out;

  float* ws   = (float*)d_ws;
  float* accp = ws;                              // 8 floats
  float* fsrc = ws + 8;                          // NPIX * FPAD
  float* fema = fsrc + (size_t)NPIX * FPAD;      // NPIX * FPAD
  float* pt   = fema + (size_t)NPIX * FPAD;      // NPIX * PPAD
  // total: (8 + 2*32768*68 + 32768*20) * 4 B ~= 19.5 MB

  hipMemsetAsync(accp, 0, 8 * sizeof(float), stream);

  feat_kernel<<<dim3(HWs / 64, Bb, 2), 256, 0, stream>>>(xsrc, xema, fsrc, fema);
  prob_kernel<<<NPIX / 256, 256, 0, stream>>>(logits, pt);
  st_kernel<<<1024, 256, 0, stream>>>(fsrc, fema, pt, gt, mix, accp);
  finish_kernel<<<1, 64, 0, stream>>>(accp, out);
}

// Round 3
// 67.934 us; speedup vs baseline: 4.2901x; 1.9949x over previous
//
#include <hip/hip_runtime.h>
#include <math.h>

typedef unsigned short u16;
typedef unsigned int   u32;

#define Bb   2
#define Cc   19
#define Hh   128
#define Ww   128
#define CHc  64
#define HWs  16384
#define NPIX 32768
#define EPSf 1e-8f
#define FSTR 72               // half stride for features (64 real + 8 zero pad), 144 B
#define PSTR 24               // half stride for probs (19 real + 5 zero pad), 48 B

typedef _Float16 h2 __attribute__((ext_vector_type(2)));

__device__ inline float fd(u32 a, u32 b, float c) {
  h2 ha = __builtin_bit_cast(h2, a);
  h2 hb = __builtin_bit_cast(h2, b);
#if __has_builtin(__builtin_amdgcn_fdot2)
  return __builtin_amdgcn_fdot2(ha, hb, c, false);
#else
  return c + (float)ha[0] * (float)hb[0] + (float)ha[1] * (float)hb[1];
#endif
}

__device__ inline u32 pk(float a, float b) {
  h2 h; h[0] = (_Float16)a; h[1] = (_Float16)b;
  return __builtin_bit_cast(u32, h);
}

// ---------- P1: normalize + transpose features -> f16 [pix][FSTR] ----------
__global__ __launch_bounds__(256) void feat_kernel(
    const float* __restrict__ xsrc, const float* __restrict__ xema,
    u16* __restrict__ osrc, u16* __restrict__ oema) {
  __shared__ float tile[64 * 65];
  __shared__ float part[256];
  __shared__ float invn[64];
  const float* in = blockIdx.z ? xema : xsrc;
  u16* out = blockIdx.z ? oema : osrc;
  int b = blockIdx.y;
  int pix0 = blockIdx.x * 64;
  int t = threadIdx.x, w = t >> 6, l = t & 63;

  const float* src = in + (size_t)b * CHc * HWs + pix0;
#pragma unroll
  for (int cc = 0; cc < 16; cc++) {
    int c = cc * 4 + w;
    tile[c * 65 + l] = src[(size_t)c * HWs + l];
  }
  __syncthreads();
  float s = 0.f;
#pragma unroll
  for (int c = w * 16; c < w * 16 + 16; c++) { float a = tile[c * 65 + l]; s += a * a; }
  part[w * 64 + l] = s;
  __syncthreads();
  if (t < 64) {
    float n = part[t] + part[64 + t] + part[128 + t] + part[192 + t];
    invn[t] = 1.0f / fmaxf(sqrtf(n), EPSf);
  }
  __syncthreads();
  // 64 px * 9 uint4 (72 halves) per block
  for (int i = t; i < 576; i += 256) {
    int px = i / 9, q = i - px * 9;
    float iv = invn[px];
    float v[8];
#pragma unroll
    for (int k = 0; k < 8; k++) {
      int c = q * 8 + k;
      v[k] = (c < CHc) ? tile[c * 65 + px] * iv : 0.f;
    }
    uint4 u = make_uint4(pk(v[0], v[1]), pk(v[2], v[3]), pk(v[4], v[5]), pk(v[6], v[7]));
    *((uint4*)(out + (size_t)(b * HWs + pix0 + px) * FSTR) + q) = u;
  }
}

// ---------- P2: softmax -> f16 [pix][PSTR] ----------
__global__ __launch_bounds__(256) void prob_kernel(
    const float* __restrict__ logits, u16* __restrict__ pt) {
  __shared__ float lp[256 * 21];
  int t = threadIdx.x;
  int gpix = blockIdx.x * 256 + t;
  int b = gpix >> 14, hw = gpix & (HWs - 1);
  const float* lg = logits + (size_t)b * Cc * HWs + hw;
  float v[Cc]; float m = -INFINITY;
#pragma unroll
  for (int c = 0; c < Cc; c++) { v[c] = lg[(size_t)c * HWs]; m = fmaxf(m, v[c]); }
  float s = 0.f;
#pragma unroll
  for (int c = 0; c < Cc; c++) { v[c] = expf(v[c] - m); s += v[c]; }
  float inv = 1.0f / s;
#pragma unroll
  for (int c = 0; c < Cc; c++) lp[t * 21 + c] = v[c] * inv;
  __syncthreads();
  u16* ob = pt + (size_t)blockIdx.x * 256 * PSTR;
  for (int i = t; i < 768; i += 256) {
    int px = i / 3, q = i - px * 3;
    float v8[8];
#pragma unroll
    for (int k = 0; k < 8; k++) {
      int c = q * 8 + k;
      v8[k] = (c < Cc) ? lp[px * 21 + c] : 0.f;
    }
    uint4 u = make_uint4(pk(v8[0], v8[1]), pk(v8[2], v8[3]), pk(v8[4], v8[5]), pk(v8[6], v8[7]));
    *((uint4*)(ob + (size_t)px * PSTR) + q) = u;
  }
}

// ---------- ST: fused src-sim + trg-topk, ONE pixel per wave ----------
__global__ __launch_bounds__(256) void st_kernel(
    const u16* __restrict__ fsrc, const u16* __restrict__ fema,
    const u16* __restrict__ pt, const int* __restrict__ gt,
    const float* __restrict__ mix, float* __restrict__ partials) {
  int bid = blockIdx.x;
  int swz = ((bid & 7) << 10) | (bid >> 3);       // 8192 % 8 == 0: bijective
  int t = threadIdx.x, wv = t >> 6, lane = t & 63;
  int pix = (swz << 2) | wv;
  int b = pix >> 14, hw = pix & (HWs - 1);
  int h = hw >> 7, w = hw & 127;
  int dh = lane / 7 - 3, dw = lane % 7 - 3;       // valid for lane < 49
  bool lact = lane < 49;
  int hn = h + dh, wn = w + dw;
  bool inb = lact && ((unsigned)hn < 128u) && ((unsigned)wn < 128u);
  int hwn = inb ? ((hn << 7) | wn) : hw;          // inactive lanes: broadcast center
  size_t bb = (size_t)b << 14;

  float psum = 0, pcnt = 0, nsum = 0, ncnt = 0, posa = 0, nega = 0, cnt = 0;

  // --- source cosine sim ---
  {
    const uint4* sc = (const uint4*)(fsrc + (bb + hw) * FSTR);
    const uint4* sn = (const uint4*)(fsrc + (bb + hwn) * FSTR);
    float d0 = 0, d1 = 0, d2 = 0, d3 = 0;
#pragma unroll
    for (int q = 0; q < 8; q += 4) {
      uint4 a0 = sc[q], b0 = sn[q], a1 = sc[q+1], b1 = sn[q+1];
      uint4 a2 = sc[q+2], b2 = sn[q+2], a3 = sc[q+3], b3 = sn[q+3];
      d0 = fd(a0.x,b0.x,d0); d0 = fd(a0.y,b0.y,d0); d0 = fd(a0.z,b0.z,d0); d0 = fd(a0.w,b0.w,d0);
      d1 = fd(a1.x,b1.x,d1); d1 = fd(a1.y,b1.y,d1); d1 = fd(a1.z,b1.z,d1); d1 = fd(a1.w,b1.w,d1);
      d2 = fd(a2.x,b2.x,d2); d2 = fd(a2.y,b2.y,d2); d2 = fd(a2.z,b2.z,d2); d2 = fd(a2.w,b2.w,d2);
      d3 = fd(a3.x,b3.x,d3); d3 = fd(a3.y,b3.y,d3); d3 = fd(a3.z,b3.z,d3); d3 = fd(a3.w,b3.w,d3);
    }
    float sims = inb ? ((d0 + d1) + (d2 + d3)) : 0.f;   // zero-pad unfold -> sim 0
    int gtc = gt[bb + hw];
    int gtn = inb ? gt[bb + hwn] : 0;                   // zero-pad unfold -> gt 0
    if (lact && gtc != 255) {
      bool pos = (gtn == gtc);
      psum = pos ? sims : 0.f; pcnt = pos ? 1.f : 0.f;
      nsum = pos ? 0.f : sims; ncnt = pos ? 0.f : 1.f;
    }
  }

  // --- target branch (wave-uniform) ---
  if (mix[bb + hw] < 0.5f) {
    const uint4* ec = (const uint4*)(fema + (bb + hw) * FSTR);
    const uint4* en = (const uint4*)(fema + (bb + hwn) * FSTR);
    float d0 = 0, d1 = 0, d2 = 0, d3 = 0;
#pragma unroll
    for (int q = 0; q < 8; q += 4) {
      uint4 a0 = ec[q], b0 = en[q], a1 = ec[q+1], b1 = en[q+1];
      uint4 a2 = ec[q+2], b2 = en[q+2], a3 = ec[q+3], b3 = en[q+3];
      d0 = fd(a0.x,b0.x,d0); d0 = fd(a0.y,b0.y,d0); d0 = fd(a0.z,b0.z,d0); d0 = fd(a0.w,b0.w,d0);
      d1 = fd(a1.x,b1.x,d1); d1 = fd(a1.y,b1.y,d1); d1 = fd(a1.z,b1.z,d1); d1 = fd(a1.w,b1.w,d1);
      d2 = fd(a2.x,b2.x,d2); d2 = fd(a2.y,b2.y,d2); d2 = fd(a2.z,b2.z,d2); d2 = fd(a2.w,b2.w,d2);
      d3 = fd(a3.x,b3.x,d3); d3 = fd(a3.y,b3.y,d3); d3 = fd(a3.z,b3.z,d3); d3 = fd(a3.w,b3.w,d3);
    }
    float dote = (d0 + d1) + (d2 + d3);
    const uint4* pc = (const uint4*)(pt + (bb + hw) * PSTR);
    const uint4* pn = (const uint4*)(pt + (bb + hwn) * PSTR);
    float p0 = 0, p1 = 0, p2 = 0;
    {
      uint4 a0 = pc[0], b0 = pn[0], a1 = pc[1], b1 = pn[1], a2 = pc[2], b2 = pn[2];
      p0 = fd(a0.x,b0.x,p0); p0 = fd(a0.y,b0.y,p0); p0 = fd(a0.z,b0.z,p0); p0 = fd(a0.w,b0.w,p0);
      p1 = fd(a1.x,b1.x,p1); p1 = fd(a1.y,b1.y,p1); p1 = fd(a1.z,b1.z,p1); p1 = fd(a1.w,b1.w,p1);
      p2 = fd(a2.x,b2.x,p2); p2 = fd(a2.y,b2.y,p2); p2 = fd(a2.z,b2.z,p2); p2 = fd(a2.w,b2.w,p2);
    }
    float dotp = (p0 + p1) + p2;

    float v  = lact ? (inb ? dote : 0.f)           : -INFINITY;
    float cp = lact ? (inb ? dotp : (1.0f / 19.f)) : 0.f;

    // bitonic sort descending by v, carrying cp
#pragma unroll
    for (int k = 2; k <= 64; k <<= 1) {
#pragma unroll
      for (int jj = k >> 1; jj; jj >>= 1) {
        float ov = __shfl_xor(v, jj);
        float oc = __shfl_xor(cp, jj);
        bool up = ((lane & k) == 0) == ((lane & jj) == 0);
        bool sw = up ? (ov > v) : (ov < v);
        if (sw) { v = ov; cp = oc; }
      }
    }
    if (lane < 9)                posa = v * cp;                    // top-9 most similar
    if (lane >= 41 && lane < 49) nega = (1.f - v) * (1.f - cp);    // bottom-8 of 49 reals
    if (lane == 0)               cnt = 1.f;
  }

  // wave butterfly reduce
#pragma unroll
  for (int off = 32; off; off >>= 1) {
    psum += __shfl_xor(psum, off); pcnt += __shfl_xor(pcnt, off);
    nsum += __shfl_xor(nsum, off); ncnt += __shfl_xor(ncnt, off);
    posa += __shfl_xor(posa, off); nega += __shfl_xor(nega, off);
    cnt  += __shfl_xor(cnt,  off);
  }
  __shared__ float sacc[4][8];
  if (lane == 0) {
    sacc[wv][0] = psum; sacc[wv][1] = pcnt; sacc[wv][2] = nsum; sacc[wv][3] = ncnt;
    sacc[wv][4] = posa; sacc[wv][5] = nega; sacc[wv][6] = cnt;  sacc[wv][7] = 0.f;
  }
  __syncthreads();
  if (t < 8) {
    partials[(size_t)bid * 8 + t] = sacc[0][t] + sacc[1][t] + sacc[2][t] + sacc[3][t];
  }
}

// ---------- F: reduce 8192 partials, combine ----------
__global__ __launch_bounds__(256) void finish_kernel(
    const float* __restrict__ partials, float* __restrict__ out) {
  int t = threadIdx.x, lane = t & 63, wv = t >> 6;
  float s0=0,s1=0,s2=0,s3=0,s4=0,s5=0,s6=0;
  for (int r = t; r < 8192; r += 256) {
    const float4* p = (const float4*)(partials + (size_t)r * 8);
    float4 x = p[0], y = p[1];
    s0 += x.x; s1 += x.y; s2 += x.z; s3 += x.w;
    s4 += y.x; s5 += y.y; s6 += y.z;
  }
#pragma unroll
  for (int off = 32; off; off >>= 1) {
    s0 += __shfl_xor(s0, off); s1 += __shfl_xor(s1, off);
    s2 += __shfl_xor(s2, off); s3 += __shfl_xor(s3, off);
    s4 += __shfl_xor(s4, off); s5 += __shfl_xor(s5, off);
    s6 += __shfl_xor(s6, off);
  }
  __shared__ float sacc[4][8];
  if (lane == 0) {
    sacc[wv][0]=s0; sacc[wv][1]=s1; sacc[wv][2]=s2; sacc[wv][3]=s3;
    sacc[wv][4]=s4; sacc[wv][5]=s5; sacc[wv][6]=s6;
  }
  __syncthreads();
  if (t == 0) {
    float a[7];
#pragma unroll
    for (int c = 0; c < 7; c++) a[c] = sacc[0][c] + sacc[1][c] + sacc[2][c] + sacc[3][c];
    float src_pos = a[0] / fmaxf(a[1], 1.0f);
    float src_neg = a[2] / fmaxf(a[3], 1.0f);
    out[0] = -src_pos;
    out[1] =  src_neg;
    out[2] = -(a[4] / fmaxf(9.0f * a[6], 1.0f));
    out[3] = -(a[5] / fmaxf(8.0f * a[6], 1.0f));
  }
}

extern "C" void kernel_launch(void* const* d_in, const int* in_sizes, int n_in,
                              void* d_out, int out_size, void* d_ws, size_t ws_size,
                              hipStream_t stream) {
  const float* logits = (const float*)d_in[0];
  const int*   gt     = (const int*)  d_in[1];
  const float* xema   = (const float*)d_in[2];
  const float* xsrc   = (const float*)d_in[3];
  const float* mix    = (const float*)d_in[4];
  float* out = (float*)d_out;

  float* partials = (float*)d_ws;                                 // 8192*8 f32 = 256 KB
  u16* fsrc = (u16*)((char*)d_ws + 8192 * 8 * sizeof(float));     // NPIX*FSTR f16 = 4.5 MB
  u16* fema = fsrc + (size_t)NPIX * FSTR;                         // 4.5 MB
  u16* pt   = fema + (size_t)NPIX * FSTR;                         // NPIX*PSTR f16 = 1.5 MB

  feat_kernel<<<dim3(HWs / 64, Bb, 2), 256, 0, stream>>>(xsrc, xema, fsrc, fema);
  prob_kernel<<<NPIX / 256, 256, 0, stream>>>(logits, pt);
  st_kernel<<<8192, 256, 0, stream>>>(fsrc, fema, pt, gt, mix, partials);
  finish_kernel<<<1, 256, 0, stream>>>(partials, out);
}

// Round 4
// 48.564 us; speedup vs baseline: 6.0013x; 1.3989x over previous
//
#include <hip/hip_runtime.h>
#include <math.h>

typedef unsigned short u16;
typedef unsigned int   u32;
typedef unsigned long long u64;

#define Bb   2
#define Cc   19
#define Hh   128
#define Ww   128
#define CHc  64
#define HWs  16384
#define NPIX 32768
#define EPSf 1e-8f
#define FSTR 72               // half stride for features (64 real + 8 zero pad), 144 B
#define PSTR 24               // half stride for probs (19 real + 5 zero pad), 48 B

typedef _Float16 h2 __attribute__((ext_vector_type(2)));

__device__ inline float fd(u32 a, u32 b, float c) {
  h2 ha = __builtin_bit_cast(h2, a);
  h2 hb = __builtin_bit_cast(h2, b);
#if __has_builtin(__builtin_amdgcn_fdot2)
  return __builtin_amdgcn_fdot2(ha, hb, c, false);
#else
  return c + (float)ha[0] * (float)hb[0] + (float)ha[1] * (float)hb[1];
#endif
}

__device__ inline u32 pk(float a, float b) {
  h2 h; h[0] = (_Float16)a; h[1] = (_Float16)b;
  return __builtin_bit_cast(u32, h);
}

// ---------- PRE: feat normalize+transpose (blocks 0..1023) | softmax (1024..1151) ----------
__global__ __launch_bounds__(256) void pre_kernel(
    const float* __restrict__ logits,
    const float* __restrict__ xsrc, const float* __restrict__ xema,
    u16* __restrict__ osrc, u16* __restrict__ oema, u16* __restrict__ pt) {
  __shared__ float smem[5376];          // 21504 B union
  int bid = blockIdx.x;
  int t = threadIdx.x;

  if (bid < 1024) {
    // ---- feature role ----
    float* tile = smem;                 // 64*65
    float* part = smem + 4160;          // 256
    float* invn = smem + 4416;          // 64
    int xb = bid & 255, b = (bid >> 8) & 1, z = bid >> 9;
    const float* in = z ? xema : xsrc;
    u16* out = z ? oema : osrc;
    int pix0 = xb * 64;
    int w = t >> 6, l = t & 63;

    const float* src = in + (size_t)b * CHc * HWs + pix0;
#pragma unroll
    for (int cc = 0; cc < 16; cc++) {
      int c = cc * 4 + w;
      tile[c * 65 + l] = src[(size_t)c * HWs + l];
    }
    __syncthreads();
    float s = 0.f;
#pragma unroll
    for (int c = w * 16; c < w * 16 + 16; c++) { float a = tile[c * 65 + l]; s += a * a; }
    part[w * 64 + l] = s;
    __syncthreads();
    if (t < 64) {
      float n = part[t] + part[64 + t] + part[128 + t] + part[192 + t];
      invn[t] = 1.0f / fmaxf(sqrtf(n), EPSf);
    }
    __syncthreads();
    for (int i = t; i < 576; i += 256) {
      int px = i / 9, q = i - px * 9;
      float iv = invn[px];
      float v[8];
#pragma unroll
      for (int k = 0; k < 8; k++) {
        int c = q * 8 + k;
        v[k] = (c < CHc) ? tile[c * 65 + px] * iv : 0.f;
      }
      uint4 u = make_uint4(pk(v[0], v[1]), pk(v[2], v[3]), pk(v[4], v[5]), pk(v[6], v[7]));
      *((uint4*)(out + (size_t)(b * HWs + pix0 + px) * FSTR) + q) = u;
    }
  } else {
    // ---- softmax role ----
    float* lp = smem;                   // 256*21
    int pb = bid - 1024;
    int gpix = pb * 256 + t;
    int b = gpix >> 14, hw = gpix & (HWs - 1);
    const float* lg = logits + (size_t)b * Cc * HWs + hw;
    float v[Cc]; float m = -INFINITY;
#pragma unroll
    for (int c = 0; c < Cc; c++) { v[c] = lg[(size_t)c * HWs]; m = fmaxf(m, v[c]); }
    float s = 0.f;
#pragma unroll
    for (int c = 0; c < Cc; c++) { v[c] = expf(v[c] - m); s += v[c]; }
    float inv = 1.0f / s;
#pragma unroll
    for (int c = 0; c < Cc; c++) lp[t * 21 + c] = v[c] * inv;
    __syncthreads();
    u16* ob = pt + (size_t)pb * 256 * PSTR;
    for (int i = t; i < 768; i += 256) {
      int px = i / 3, q = i - px * 3;
      float v8[8];
#pragma unroll
      for (int k = 0; k < 8; k++) {
        int c = q * 8 + k;
        v8[k] = (c < Cc) ? lp[px * 21 + c] : 0.f;
      }
      uint4 u = make_uint4(pk(v8[0], v8[1]), pk(v8[2], v8[3]), pk(v8[4], v8[5]), pk(v8[6], v8[7]));
      *((uint4*)(ob + (size_t)px * PSTR) + q) = u;
    }
  }
}

// ---------- ST: fused src-sim + trg rank-select, ONE pixel per wave ----------
__global__ __launch_bounds__(256) void st_kernel(
    const u16* __restrict__ fsrc, const u16* __restrict__ fema,
    const u16* __restrict__ pt, const int* __restrict__ gt,
    const float* __restrict__ mix, float* __restrict__ partials) {
  __shared__ u64 ksh[4][66];            // per-wave sortable keys (row 528 B, 16B-mult)
  __shared__ float sacc[4][8];
  int bid = blockIdx.x;
  int swz = ((bid & 7) << 10) | (bid >> 3);        // 8192 % 8 == 0: bijective
  int t = threadIdx.x, wv = t >> 6, lane = t & 63;
  int pix = __builtin_amdgcn_readfirstlane((swz << 2) | wv);  // wave-uniform, scalar
  int b = pix >> 14, hw = pix & (HWs - 1);
  int h = hw >> 7, w = hw & 127;
  int dh = lane / 7 - 3, dw = lane % 7 - 3;
  bool lact = lane < 49;
  int hn = h + dh, wn = w + dw;
  bool inb = lact && ((unsigned)hn < 128u) && ((unsigned)wn < 128u);
  int hwn = inb ? ((hn << 7) | wn) : hw;
  size_t bb = (size_t)b << 14;

  float psum = 0, ssum = 0, posa = 0, nega = 0, pcntW = 0, vcntW = 0, cntW = 0;

  // ---- source cosine sim ----
  {
    const uint4* sc = (const uint4*)(fsrc + (bb + hw) * FSTR);   // scalar base
    const uint4* sn = (const uint4*)(fsrc + (bb + hwn) * FSTR);  // per-lane gather
    float d0 = 0, d1 = 0, d2 = 0, d3 = 0;
#pragma unroll
    for (int q = 0; q < 8; q += 4) {
      uint4 a0 = sc[q], b0 = sn[q], a1 = sc[q+1], b1 = sn[q+1];
      uint4 a2 = sc[q+2], b2 = sn[q+2], a3 = sc[q+3], b3 = sn[q+3];
      d0 = fd(a0.x,b0.x,d0); d0 = fd(a0.y,b0.y,d0); d0 = fd(a0.z,b0.z,d0); d0 = fd(a0.w,b0.w,d0);
      d1 = fd(a1.x,b1.x,d1); d1 = fd(a1.y,b1.y,d1); d1 = fd(a1.z,b1.z,d1); d1 = fd(a1.w,b1.w,d1);
      d2 = fd(a2.x,b2.x,d2); d2 = fd(a2.y,b2.y,d2); d2 = fd(a2.z,b2.z,d2); d2 = fd(a2.w,b2.w,d2);
      d3 = fd(a3.x,b3.x,d3); d3 = fd(a3.y,b3.y,d3); d3 = fd(a3.z,b3.z,d3); d3 = fd(a3.w,b3.w,d3);
    }
    int gtc = __builtin_amdgcn_readfirstlane(gt[bb + hw]);
    if (gtc != 255) {                    // scalar branch
      float sims = inb ? ((d0 + d1) + (d2 + d3)) : 0.f;  // zero-pad unfold -> sim 0
      int gtn = inb ? gt[bb + hwn] : 0;                  // zero-pad unfold -> gt 0
      bool pos = (gtn == gtc);
      if (lact) { ssum = sims; if (pos) psum = sims; }
      u64 mk = __ballot(lact && pos);
      pcntW = (float)__popcll(mk);
      vcntW = 1.f;
    }
  }

  // ---- target branch (wave-uniform) ----
  u32 mixu = __builtin_amdgcn_readfirstlane(__float_as_uint(mix[bb + hw]));
  if (__uint_as_float(mixu) < 0.5f) {
    const uint4* ec = (const uint4*)(fema + (bb + hw) * FSTR);
    const uint4* en = (const uint4*)(fema + (bb + hwn) * FSTR);
    float d0 = 0, d1 = 0, d2 = 0, d3 = 0;
#pragma unroll
    for (int q = 0; q < 8; q += 4) {
      uint4 a0 = ec[q], b0 = en[q], a1 = ec[q+1], b1 = en[q+1];
      uint4 a2 = ec[q+2], b2 = en[q+2], a3 = ec[q+3], b3 = en[q+3];
      d0 = fd(a0.x,b0.x,d0); d0 = fd(a0.y,b0.y,d0); d0 = fd(a0.z,b0.z,d0); d0 = fd(a0.w,b0.w,d0);
      d1 = fd(a1.x,b1.x,d1); d1 = fd(a1.y,b1.y,d1); d1 = fd(a1.z,b1.z,d1); d1 = fd(a1.w,b1.w,d1);
      d2 = fd(a2.x,b2.x,d2); d2 = fd(a2.y,b2.y,d2); d2 = fd(a2.z,b2.z,d2); d2 = fd(a2.w,b2.w,d2);
      d3 = fd(a3.x,b3.x,d3); d3 = fd(a3.y,b3.y,d3); d3 = fd(a3.z,b3.z,d3); d3 = fd(a3.w,b3.w,d3);
    }
    float dote = (d0 + d1) + (d2 + d3);
    const uint4* pc = (const uint4*)(pt + (bb + hw) * PSTR);
    const uint4* pn = (const uint4*)(pt + (bb + hwn) * PSTR);
    float p0 = 0, p1 = 0, p2 = 0;
    {
      uint4 a0 = pc[0], b0 = pn[0], a1 = pc[1], b1 = pn[1], a2 = pc[2], b2 = pn[2];
      p0 = fd(a0.x,b0.x,p0); p0 = fd(a0.y,b0.y,p0); p0 = fd(a0.z,b0.z,p0); p0 = fd(a0.w,b0.w,p0);
      p1 = fd(a1.x,b1.x,p1); p1 = fd(a1.y,b1.y,p1); p1 = fd(a1.z,b1.z,p1); p1 = fd(a1.w,b1.w,p1);
      p2 = fd(a2.x,b2.x,p2); p2 = fd(a2.y,b2.y,p2); p2 = fd(a2.z,b2.z,p2); p2 = fd(a2.w,b2.w,p2);
    }
    float dotp = (p0 + p1) + p2;

    float v  = inb ? dote : 0.f;
    float cp = inb ? dotp : (1.0f / 19.f);

    // sortable key: monotone f32 bits + lane in LSBs (all 49 keys distinct)
    u32 bits = __float_as_uint(v);
    u32 mono = (bits & 0x80000000u) ? ~bits : (bits | 0x80000000u);
    u64 k64 = ((u64)mono << 6) | (u32)lane;
    ksh[wv][lane] = k64;
    // stable descending rank via pipelined LDS broadcast reads
    int rd = 0;
#pragma unroll
    for (int j = 0; j < 48; j += 2) {
      ulonglong2 q = *(const ulonglong2*)&ksh[wv][j];
      rd += (q.x > k64);
      rd += (q.y > k64);
    }
    rd += (ksh[wv][48] > k64);
    if (lact) {
      if (rd < 9)   posa = v * cp;                       // top-9 most similar
      if (rd >= 41) nega = (1.f - v) * (1.f - cp);       // bottom-8 (rank_asc = 48-rd < 8)
    }
    cntW = 1.f;
  }

  // butterfly reduce 4 float sums (independent chains)
#pragma unroll
  for (int off = 32; off; off >>= 1) {
    psum += __shfl_xor(psum, off); ssum += __shfl_xor(ssum, off);
    posa += __shfl_xor(posa, off); nega += __shfl_xor(nega, off);
  }
  if (lane == 0) {
    sacc[wv][0] = psum;  sacc[wv][1] = pcntW; sacc[wv][2] = ssum;
    sacc[wv][3] = posa;  sacc[wv][4] = nega;  sacc[wv][5] = vcntW;
    sacc[wv][6] = cntW;  sacc[wv][7] = 0.f;
  }
  __syncthreads();
  if (t < 8) {
    partials[(size_t)bid * 8 + t] = sacc[0][t] + sacc[1][t] + sacc[2][t] + sacc[3][t];
  }
}

// ---------- F: reduce 8192 partials, combine ----------
__global__ __launch_bounds__(256) void finish_kernel(
    const float* __restrict__ partials, float* __restrict__ out) {
  int t = threadIdx.x, lane = t & 63, wv = t >> 6;
  float s0=0,s1=0,s2=0,s3=0,s4=0,s5=0,s6=0;
  for (int r = t; r < 8192; r += 256) {
    const float4* p = (const float4*)(partials + (size_t)r * 8);
    float4 x = p[0], y = p[1];
    s0 += x.x; s1 += x.y; s2 += x.z; s3 += x.w;
    s4 += y.x; s5 += y.y; s6 += y.z;
  }
#pragma unroll
  for (int off = 32; off; off >>= 1) {
    s0 += __shfl_xor(s0, off); s1 += __shfl_xor(s1, off);
    s2 += __shfl_xor(s2, off); s3 += __shfl_xor(s3, off);
    s4 += __shfl_xor(s4, off); s5 += __shfl_xor(s5, off);
    s6 += __shfl_xor(s6, off);
  }
  __shared__ float sacc[4][8];
  if (lane == 0) {
    sacc[wv][0]=s0; sacc[wv][1]=s1; sacc[wv][2]=s2; sacc[wv][3]=s3;
    sacc[wv][4]=s4; sacc[wv][5]=s5; sacc[wv][6]=s6;
  }
  __syncthreads();
  if (t == 0) {
    float a[7];
#pragma unroll
    for (int c = 0; c < 7; c++) a[c] = sacc[0][c] + sacc[1][c] + sacc[2][c] + sacc[3][c];
    float psum = a[0], pcnt = a[1], ssum = a[2];
    float posa = a[3], nega = a[4], vcnt = a[5], cnt = a[6];
    float nsum = ssum - psum;
    float ncnt = 49.f * vcnt - pcnt;
    out[0] = -(psum / fmaxf(pcnt, 1.0f));
    out[1] =  (nsum / fmaxf(ncnt, 1.0f));
    out[2] = -(posa / fmaxf(9.0f * cnt, 1.0f));
    out[3] = -(nega / fmaxf(8.0f * cnt, 1.0f));
  }
}

extern "C" void kernel_launch(void* const* d_in, const int* in_sizes, int n_in,
                              void* d_out, int out_size, void* d_ws, size_t ws_size,
                              hipStream_t stream) {
  const float* logits = (const float*)d_in[0];
  const int*   gt     = (const int*)  d_in[1];
  const float* xema   = (const float*)d_in[2];
  const float* xsrc   = (const float*)d_in[3];
  const float* mix    = (const float*)d_in[4];
  float* out = (float*)d_out;

  float* partials = (float*)d_ws;                                 // 8192*8 f32 = 256 KB
  u16* fsrc = (u16*)((char*)d_ws + 8192 * 8 * sizeof(float));     // NPIX*FSTR f16 = 4.5 MB
  u16* fema = fsrc + (size_t)NPIX * FSTR;                         // 4.5 MB
  u16* pt   = fema + (size_t)NPIX * FSTR;                         // NPIX*PSTR f16 = 1.5 MB

  pre_kernel<<<1152, 256, 0, stream>>>(logits, xsrc, xema, fsrc, fema, pt);
  st_kernel<<<8192, 256, 0, stream>>>(fsrc, fema, pt, gt, mix, partials);
  finish_kernel<<<1, 256, 0, stream>>>(partials, out);
}